// Round 5
// baseline (40.750 us; speedup 1.0000x reference)
//
#include <hip/hip_runtime.h>

// 16 x 8 x 512 x 512 fp32; 2x2 grey opening + MSE (scalar out)
#define IMG_H 512
#define IMG_W 512
#define NIMG 128
#define CHUNK 16
#define NCHUNK (IMG_H / CHUNK)          // 32
#define THREADS 256
#define WPB (THREADS / 64)              // 4 waves / block
#define NBLOCKS (NIMG * NCHUNK / WPB)   // 1024 -> 4 blocks/CU if VGPR<=128

// NOTE: no __launch_bounds__ minimum — R3/R4 showed the (256,4) cap pushes the
// allocator into scratch spills (R3: 75 MB WRITE_SIZE on a read-only kernel).
// Natural allocation ~80-100 VGPR already yields 16 waves/CU.
__global__ __launch_bounds__(THREADS)
void opening_mse_kernel(const float* __restrict__ X, float* __restrict__ out) {
    const int lane = threadIdx.x & 63;
    const int gw   = blockIdx.x * WPB + (threadIdx.x >> 6);
    const int n     = gw >> 5;               // image 0..127
    const int chunk = gw & (NCHUNK - 1);     // 0..31
    const int s = chunk * CHUNK;
    const int e = s + CHUNK;                 // output rows [s, e)
    const float* __restrict__ img = X + (size_t)n * (IMG_H * IMG_W);
    const int cb = lane << 3;                // 8 cols/lane; wave spans 512 cols

    auto ld = [&](int r, float4& a, float4& b) {
        const float* __restrict__ p = img + (size_t)r * IMG_W + cb;
        a = *reinterpret_cast<const float4*>(p);
        b = *reinterpret_cast<const float4*>(p + 4);
    };

    // h[k] = min(x[c-1], x[c]) for c = cb+k, k=0..8; h[8] is the dilation's
    // right-neighbor column (lane 63: h[8]=h[7] == reflect clamp at col 511).
    auto mkh = [&](const float4& a, const float4& b, float (&h)[9]) {
        float xl = __shfl_up(b.w, 1, 64);
        if (lane == 0) xl = a.x;
        float xr = __shfl_down(a.x, 1, 64);
        h[0] = fminf(xl, a.x);
        h[1] = fminf(a.x, a.y);
        h[2] = fminf(a.y, a.z);
        h[3] = fminf(a.z, a.w);
        h[4] = fminf(a.w, b.x);
        h[5] = fminf(b.x, b.y);
        h[6] = fminf(b.y, b.z);
        h[7] = fminf(b.z, b.w);
        h[8] = (lane == 63) ? h[7] : fminf(b.w, xr);
    };

    float hprev[9], hd[8];
    float4 xa, xb;   // x of the row whose opened value we emit next (row a-1)

    {   // prime: h(row s-1 clamped), h(row s), hd[s]
        float4 ta, tb;
        ld(s > 0 ? s - 1 : 0, ta, tb);
        mkh(ta, tb, hprev);
        ld(s, xa, xb);
        float hcur[9], E[9];
        mkh(xa, xb, hcur);
        #pragma unroll
        for (int k = 0; k < 9; ++k) E[k] = fminf(hprev[k], hcur[k]);
        #pragma unroll
        for (int k = 0; k < 8; ++k) hd[k] = fmaxf(E[k], E[k + 1]);
        #pragma unroll
        for (int k = 0; k < 9; ++k) hprev[k] = hcur[k];
    }

    // depth-2 register ring of row prefetches (s+1, s+2 always < IMG_H: s<=496)
    float4 p1a, p1b, p2a, p2b;
    ld(s + 1, p1a, p1b);
    ld(s + 2, p2a, p2b);

    float acc = 0.0f;
    #pragma unroll 2
    for (int a = s + 1; a <= e; ++a) {
        float4 ca = p1a, cbv = p1b;
        p1a = p2a; p1b = p2b;
        int rn = a + 2;                       // branch-free clamp; overshoot rows
        rn = rn < IMG_H ? rn : IMG_H - 1;     // are L2-shared with next chunk
        ld(rn, p2a, p2b);

        float hdc[8];
        if (a < IMG_H) {
            float hcur[9], E[9];
            mkh(ca, cbv, hcur);
            #pragma unroll
            for (int k = 0; k < 9; ++k) E[k] = fminf(hprev[k], hcur[k]);
            #pragma unroll
            for (int k = 0; k < 8; ++k) hdc[k] = fmaxf(E[k], E[k + 1]);
            #pragma unroll
            for (int k = 0; k < 9; ++k) hprev[k] = hcur[k];
        } else {
            #pragma unroll
            for (int k = 0; k < 8; ++k) hdc[k] = hd[k];   // hd[H] := hd[H-1]
        }

        // opened row a-1 = max(hd[a-1], hd[a]); accumulate squared error vs x
        float d;
        d = xa.x - fmaxf(hd[0], hdc[0]); acc = fmaf(d, d, acc);
        d = xa.y - fmaxf(hd[1], hdc[1]); acc = fmaf(d, d, acc);
        d = xa.z - fmaxf(hd[2], hdc[2]); acc = fmaf(d, d, acc);
        d = xa.w - fmaxf(hd[3], hdc[3]); acc = fmaf(d, d, acc);
        d = xb.x - fmaxf(hd[4], hdc[4]); acc = fmaf(d, d, acc);
        d = xb.y - fmaxf(hd[5], hdc[5]); acc = fmaf(d, d, acc);
        d = xb.z - fmaxf(hd[6], hdc[6]); acc = fmaf(d, d, acc);
        d = xb.w - fmaxf(hd[7], hdc[7]); acc = fmaf(d, d, acc);

        #pragma unroll
        for (int k = 0; k < 8; ++k) hd[k] = hdc[k];
        xa = ca; xb = cbv;
    }

    // wave shuffle reduce -> LDS across 4 waves -> one atomic per block
    #pragma unroll
    for (int off = 32; off > 0; off >>= 1)
        acc += __shfl_down(acc, off, 64);

    __shared__ float wsum[WPB];
    const int wid = threadIdx.x >> 6;
    if (lane == 0) wsum[wid] = acc;
    __syncthreads();
    if (threadIdx.x == 0) {
        float sblk = wsum[0] + wsum[1] + wsum[2] + wsum[3];
        atomicAdd(out, sblk * (1.0f / 33554432.0f));   // / 2^25 -> mean
    }
}

extern "C" void kernel_launch(void* const* d_in, const int* in_sizes, int n_in,
                              void* d_out, int out_size, void* d_ws, size_t ws_size,
                              hipStream_t stream) {
    const float* X = (const float*)d_in[0];
    float* out = (float*)d_out;
    hipMemsetAsync(out, 0, sizeof(float), stream);
    opening_mse_kernel<<<NBLOCKS, THREADS, 0, stream>>>(X, out);
}

// Round 6
// 33.799 us; speedup vs baseline: 1.2057x; 1.2057x over previous
//
#include <hip/hip_runtime.h>

// 16 x 8 x 512 x 512 fp32; 2x2 grey opening + MSE (scalar out)
#define IMG_H 512
#define IMG_W 512
#define NIMG 128
#define CHUNK 32
#define NCHUNK (IMG_H / CHUNK)          // 16
#define THREADS 256
#define WPB (THREADS / 64)              // 4 waves / block
#define NBLOCKS (NIMG * NCHUNK / WPB)   // 512

// No __launch_bounds__ minimum: R3 showed the (256,4) cap causes scratch
// spills (75 MB writes on a read-only kernel). Natural alloc ~95 VGPR.
__global__ __launch_bounds__(THREADS)
void opening_mse_kernel(const float* __restrict__ X, float* __restrict__ out) {
    const int lane = threadIdx.x & 63;
    const int gw   = blockIdx.x * WPB + (threadIdx.x >> 6);
    const int n     = gw >> 4;               // image 0..127
    const int chunk = gw & (NCHUNK - 1);     // 0..15
    const int s = chunk * CHUNK;
    const int e = s + CHUNK;                 // output rows [s, e)
    const float* __restrict__ img = X + (size_t)n * (IMG_H * IMG_W);
    const int cb = lane << 3;                // 8 cols/lane; wave spans 512 cols
    // clamp target for overshoot prefetch: a row we already loaded (L1 hit)
    const int rmax = (e < IMG_H) ? e : (IMG_H - 1);

    auto ld = [&](int r, float4& a, float4& b) {
        const float* __restrict__ p = img + (size_t)r * IMG_W + cb;
        a = *reinterpret_cast<const float4*>(p);
        b = *reinterpret_cast<const float4*>(p + 4);
    };

    // h[k] = min(x[c-1], x[c]) for c = cb+k, k=0..8; h[8] is the dilation's
    // right-neighbor column (lane 63: h[8]=h[7] == reflect clamp at col 511).
    auto mkh = [&](const float4& a, const float4& b, float (&h)[9]) {
        float xl = __shfl_up(b.w, 1, 64);
        if (lane == 0) xl = a.x;
        float xr = __shfl_down(a.x, 1, 64);
        h[0] = fminf(xl, a.x);
        h[1] = fminf(a.x, a.y);
        h[2] = fminf(a.y, a.z);
        h[3] = fminf(a.z, a.w);
        h[4] = fminf(a.w, b.x);
        h[5] = fminf(b.x, b.y);
        h[6] = fminf(b.y, b.z);
        h[7] = fminf(b.z, b.w);
        h[8] = (lane == 63) ? h[7] : fminf(b.w, xr);
    };

    float hprev[9], hd[8];
    float4 xa, xb;   // x of the row whose opened value we emit next

    {   // prime: h(row s-1 clamped), h(row s), hd[s]
        float4 ta, tb;
        ld(s > 0 ? s - 1 : 0, ta, tb);
        mkh(ta, tb, hprev);
        ld(s, xa, xb);
        float hcur[9], E[9];
        mkh(xa, xb, hcur);
        #pragma unroll
        for (int k = 0; k < 9; ++k) E[k] = fminf(hprev[k], hcur[k]);
        #pragma unroll
        for (int k = 0; k < 8; ++k) hd[k] = fmaxf(E[k], E[k + 1]);
        #pragma unroll
        for (int k = 0; k < 9; ++k) hprev[k] = hcur[k];
    }

    // depth-2 ring of ROW PAIRS: 4 rows (8 KB/wave) in flight
    float4 q1a0, q1b0, q1a1, q1b1;   // rows a0, a1 of next iteration
    float4 q2a0, q2b0, q2a1, q2b1;   // the pair after that
    ld(s + 1, q1a0, q1b0);
    ld(s + 2, q1a1, q1b1);
    ld(s + 3, q2a0, q2b0);
    ld(s + 4, q2a1, q2b1);           // s+4 <= 484 < IMG_H always

    float acc = 0.0f;
    #pragma unroll 2
    for (int t = 0; t < CHUNK / 2; ++t) {
        const int a0 = s + 1 + 2 * t;
        const int a1 = a0 + 1;

        // consume pair q1, shift ring, issue next pair (clamped to rmax)
        float4 c0a = q1a0, c0b = q1b0, c1a = q1a1, c1b = q1b1;
        q1a0 = q2a0; q1b0 = q2b0; q1a1 = q2a1; q1b1 = q2b1;
        int r0 = a0 + 4; r0 = r0 < rmax ? r0 : rmax;
        int r1 = a0 + 5; r1 = r1 < rmax ? r1 : rmax;
        ld(r0, q2a0, q2b0);
        ld(r1, q2a1, q2b1);

        // ---- row a0 (always < IMG_H since a0 <= s+31 <= 511)
        float h0[9], hd0[8];
        {
            float E[9];
            mkh(c0a, c0b, h0);
            #pragma unroll
            for (int k = 0; k < 9; ++k) E[k] = fminf(hprev[k], h0[k]);
            #pragma unroll
            for (int k = 0; k < 8; ++k) hd0[k] = fmaxf(E[k], E[k + 1]);
        }
        // opened(a0-1) = max(hd, hd0) vs x(a0-1) = xa/xb
        {
            float d;
            d = xa.x - fmaxf(hd[0], hd0[0]); acc = fmaf(d, d, acc);
            d = xa.y - fmaxf(hd[1], hd0[1]); acc = fmaf(d, d, acc);
            d = xa.z - fmaxf(hd[2], hd0[2]); acc = fmaf(d, d, acc);
            d = xa.w - fmaxf(hd[3], hd0[3]); acc = fmaf(d, d, acc);
            d = xb.x - fmaxf(hd[4], hd0[4]); acc = fmaf(d, d, acc);
            d = xb.y - fmaxf(hd[5], hd0[5]); acc = fmaf(d, d, acc);
            d = xb.z - fmaxf(hd[6], hd0[6]); acc = fmaf(d, d, acc);
            d = xb.w - fmaxf(hd[7], hd0[7]); acc = fmaf(d, d, acc);
        }

        // ---- row a1 (a1 == IMG_H only at t=15 of the last chunk)
        float h1[9], hd1[8];
        if (a1 < IMG_H) {
            float E[9];
            mkh(c1a, c1b, h1);
            #pragma unroll
            for (int k = 0; k < 9; ++k) E[k] = fminf(h0[k], h1[k]);
            #pragma unroll
            for (int k = 0; k < 8; ++k) hd1[k] = fmaxf(E[k], E[k + 1]);
            #pragma unroll
            for (int k = 0; k < 9; ++k) hprev[k] = h1[k];
        } else {
            #pragma unroll
            for (int k = 0; k < 8; ++k) hd1[k] = hd0[k];   // hd[H] := hd[H-1]
        }
        // opened(a1-1) = max(hd0, hd1) vs x(a1-1) = c0
        {
            float d;
            d = c0a.x - fmaxf(hd0[0], hd1[0]); acc = fmaf(d, d, acc);
            d = c0a.y - fmaxf(hd0[1], hd1[1]); acc = fmaf(d, d, acc);
            d = c0a.z - fmaxf(hd0[2], hd1[2]); acc = fmaf(d, d, acc);
            d = c0a.w - fmaxf(hd0[3], hd1[3]); acc = fmaf(d, d, acc);
            d = c0b.x - fmaxf(hd0[4], hd1[4]); acc = fmaf(d, d, acc);
            d = c0b.y - fmaxf(hd0[5], hd1[5]); acc = fmaf(d, d, acc);
            d = c0b.z - fmaxf(hd0[6], hd1[6]); acc = fmaf(d, d, acc);
            d = c0b.w - fmaxf(hd0[7], hd1[7]); acc = fmaf(d, d, acc);
        }

        #pragma unroll
        for (int k = 0; k < 8; ++k) hd[k] = hd1[k];
        xa = c1a; xb = c1b;
    }

    // wave shuffle reduce -> LDS across 4 waves -> one atomic per block
    #pragma unroll
    for (int off = 32; off > 0; off >>= 1)
        acc += __shfl_down(acc, off, 64);

    __shared__ float wsum[WPB];
    const int wid = threadIdx.x >> 6;
    if (lane == 0) wsum[wid] = acc;
    __syncthreads();
    if (threadIdx.x == 0) {
        float sblk = wsum[0] + wsum[1] + wsum[2] + wsum[3];
        atomicAdd(out, sblk * (1.0f / 33554432.0f));   // / 2^25 -> mean
    }
}

extern "C" void kernel_launch(void* const* d_in, const int* in_sizes, int n_in,
                              void* d_out, int out_size, void* d_ws, size_t ws_size,
                              hipStream_t stream) {
    const float* X = (const float*)d_in[0];
    float* out = (float*)d_out;
    hipMemsetAsync(out, 0, sizeof(float), stream);
    opening_mse_kernel<<<NBLOCKS, THREADS, 0, stream>>>(X, out);
}